// Round 2
// baseline (185.993 us; speedup 1.0000x reference)
//
#include <hip/hip_runtime.h>

// Model: generalized multinomial clique objective over 2- and 3-simplices.
// out = 2*obj2 + 4*obj3 where
//   obj2 = sum_edges (1 - 0.5 * p.q)
//   obj3 = sum_tris  (2 - p.q - p.r - q.r + (4/3) * sum_a p_a q_a r_a)
// with P = row-softmax of the scattered node-parameter matrix (n_L == 4).
//
// R1: removed same-cache-line atomics (were 34 cyc/atomic serialized).
// R2: occupancy was grid-limited (8 items/thread -> 489 blocks -> 24%).
//     4 items/thread + fused edge+tri kernel -> ~3k blocks, full occupancy,
//     both gather streams overlap.
// R3 FAILED: nontemporal index/input streams: 112.4 -> 118.4 us. P stays
//     L2-resident without help (1.6 MB hot vs 4 MB/XCD); nt reverted.
// R4 (this round): gather request count (7M random 16B rows) is irreducible
//     and rate-bound at ~1-4 cyc/line-request per CU; remaining controllable
//     time is dispatch count. Fold final_combine into gather_reduce via
//     last-block-done ticket (release fence -> device-scope atomic ->
//     acquire fence). Combine loop is bit-identical to the old kernel, so
//     absmax stays 0.0.

#define NL 4

__device__ __forceinline__ float dot4(float4 a, float4 b) {
    return a.x * b.x + a.y * b.y + a.z * b.z + a.w * b.w;
}

__global__ void softmax_rows(const float* __restrict__ trainable,
                             const float* __restrict__ fixedp,
                             const int* __restrict__ fixed_idx,
                             float* __restrict__ P,
                             unsigned* __restrict__ ticket,
                             int n_fixed, int n_total) {
    int i = blockIdx.x * blockDim.x + threadIdx.x;
    if (i == 0) *ticket = 0u;  // zero the done-counter for gather_reduce
    if (i >= n_total) return;
    float4 v;
    int dst;
    if (i < n_fixed) {
        v = ((const float4*)fixedp)[i];
        dst = fixed_idx[i];
    } else {
        v = ((const float4*)trainable)[i - n_fixed];
        dst = i;  // trainable_indices = arange(n_fixed, n_V)
    }
    float m = fmaxf(fmaxf(v.x, v.y), fmaxf(v.z, v.w));
    float ex = __expf(v.x - m), ey = __expf(v.y - m);
    float ez = __expf(v.z - m), ew = __expf(v.w - m);
    float inv = 1.0f / (ex + ey + ez + ew);
    // P is immediately re-read ~70x per XCD by gather_reduce: keep cached.
    ((float4*)P)[dst] = make_float4(ex * inv, ey * inv, ez * inv, ew * inv);
}

// Fused gather-reduce + last-block final combine.
// Blocks [0, nb2): 4 edges/thread. Blocks [nb2, nb2+nb3): 4 triples/thread.
// Block partials to distinct slots (deterministic); the last block to finish
// re-reduces the partials with the exact loop structure of the old
// final_combine kernel (bit-identical result).
__global__ void gather_reduce(const int* __restrict__ s2, int S2, int nb2,
                              const int* __restrict__ s3, int S3, int nb3,
                              const float* __restrict__ P,
                              float* __restrict__ part2,
                              float* __restrict__ part3,
                              unsigned* __restrict__ ticket,
                              float* __restrict__ out,
                              float S2f, float S3f) {
    const float4* __restrict__ Pv = (const float4*)P;
    __shared__ float lds[12];
    __shared__ unsigned done;
    int wid = threadIdx.x >> 6;

    if ((int)blockIdx.x < nb2) {
        int tid = blockIdx.x * blockDim.x + threadIdx.x;
        int base = tid * 4;
        float sum = 0.f;
        if (base + 4 <= S2) {
            const int4* s = (const int4*)s2;
            int4 a = s[tid * 2], b = s[tid * 2 + 1];
            float4 p0 = Pv[a.x], q0 = Pv[a.y];
            float4 p1 = Pv[a.z], q1 = Pv[a.w];
            float4 p2 = Pv[b.x], q2 = Pv[b.y];
            float4 p3 = Pv[b.z], q3 = Pv[b.w];
            sum = dot4(p0, q0) + dot4(p1, q1) + dot4(p2, q2) + dot4(p3, q3);
        } else {
            for (int e = base; e < S2; ++e)
                sum += dot4(Pv[s2[2 * e]], Pv[s2[2 * e + 1]]);
        }
        #pragma unroll
        for (int off = 32; off > 0; off >>= 1) sum += __shfl_down(sum, off, 64);
        if ((threadIdx.x & 63) == 0) lds[wid] = sum;
        __syncthreads();
        if (threadIdx.x == 0)
            part2[blockIdx.x] = lds[0] + lds[1] + lds[2] + lds[3];
    } else {
        int bb = blockIdx.x - nb2;
        int tid = bb * blockDim.x + threadIdx.x;
        int base = tid * 4;
        float s_uvw = 0.f, s_t = 0.f;
        if (base + 4 <= S3) {
            const int4* s = (const int4*)s3;
            int4 a = s[tid * 3], b = s[tid * 3 + 1], c = s[tid * 3 + 2];
            int i0[4] = {a.x, a.w, b.z, c.y};
            int i1[4] = {a.y, b.x, b.w, c.z};
            int i2[4] = {a.z, b.y, c.x, c.w};
            float4 pp[4], qq[4], rr[4];
            #pragma unroll
            for (int k = 0; k < 4; ++k) {
                pp[k] = Pv[i0[k]]; qq[k] = Pv[i1[k]]; rr[k] = Pv[i2[k]];
            }
            #pragma unroll
            for (int k = 0; k < 4; ++k) {
                float4 p = pp[k], q = qq[k], r = rr[k];
                s_uvw += dot4(p, q) + dot4(p, r) + dot4(q, r);
                s_t += p.x * q.x * r.x + p.y * q.y * r.y
                     + p.z * q.z * r.z + p.w * q.w * r.w;
            }
        } else {
            for (int e = base; e < S3; ++e) {
                float4 p = Pv[s3[3 * e]], q = Pv[s3[3 * e + 1]], r = Pv[s3[3 * e + 2]];
                s_uvw += dot4(p, q) + dot4(p, r) + dot4(q, r);
                s_t += p.x * q.x * r.x + p.y * q.y * r.y
                     + p.z * q.z * r.z + p.w * q.w * r.w;
            }
        }
        #pragma unroll
        for (int off = 32; off > 0; off >>= 1) {
            s_uvw += __shfl_down(s_uvw, off, 64);
            s_t   += __shfl_down(s_t,   off, 64);
        }
        if ((threadIdx.x & 63) == 0) { lds[wid] = s_uvw; lds[4 + wid] = s_t; }
        __syncthreads();
        if (threadIdx.x == 0) {
            part3[2 * bb]     = lds[0] + lds[1] + lds[2] + lds[3];
            part3[2 * bb + 1] = lds[4] + lds[5] + lds[6] + lds[7];
        }
    }

    // ---- last-block-done final combine (replaces final_combine kernel) ----
    if (threadIdx.x == 0) {
        __threadfence();                 // release: partial visible device-wide
        done = atomicAdd(ticket, 1u);    // device-scope RMW
    }
    __syncthreads();
    if (done == (unsigned)(nb2 + nb3 - 1)) {   // block-uniform branch
        __threadfence();                 // acquire: see all partials
        float dot2 = 0.f, uvw = 0.f, t = 0.f;
        for (int i = threadIdx.x; i < nb2; i += 256) dot2 += part2[i];
        for (int i = threadIdx.x; i < nb3; i += 256) {
            uvw += part3[2 * i];
            t   += part3[2 * i + 1];
        }
        #pragma unroll
        for (int off = 32; off > 0; off >>= 1) {
            dot2 += __shfl_down(dot2, off, 64);
            uvw  += __shfl_down(uvw,  off, 64);
            t    += __shfl_down(t,    off, 64);
        }
        __syncthreads();                 // lds reuse guard
        if ((threadIdx.x & 63) == 0) {
            lds[wid] = dot2; lds[4 + wid] = uvw; lds[8 + wid] = t;
        }
        __syncthreads();
        if (threadIdx.x == 0) {
            float D = lds[0] + lds[1] + lds[2] + lds[3];
            float U = lds[4] + lds[5] + lds[6] + lds[7];
            float T = lds[8] + lds[9] + lds[10] + lds[11];
            float obj2 = S2f - 0.5f * D;
            float obj3 = 2.f * S3f - U + (4.f / 3.f) * T;
            out[0] = 2.f * obj2 + 4.f * obj3;
        }
    }
}

extern "C" void kernel_launch(void* const* d_in, const int* in_sizes, int n_in,
                              void* d_out, int out_size, void* d_ws, size_t ws_size,
                              hipStream_t stream) {
    const float* trainable = (const float*)d_in[0];
    const float* fixedp    = (const float*)d_in[1];
    const int*   fixed_idx = (const int*)d_in[2];
    const int*   s2        = (const int*)d_in[3];
    const int*   s3        = (const int*)d_in[4];

    int n_fixed = in_sizes[2];
    int n_L     = in_sizes[1] / n_fixed;   // == 4
    int n_train = in_sizes[0] / n_L;
    int n_V     = n_fixed + n_train;
    int S2      = in_sizes[3] / 2;
    int S3      = in_sizes[4] / 3;
    (void)n_L; (void)ws_size; (void)n_in; (void)out_size;

    float* P     = (float*)d_ws;                  // n_V * 4 floats
    float* part2 = P + (size_t)n_V * NL;
    int threads2 = (S2 + 3) / 4;
    int nb2      = (threads2 + 255) / 256;
    float* part3 = part2 + nb2;
    int threads3 = (S3 + 3) / 4;
    int nb3      = (threads3 + 255) / 256;
    unsigned* ticket = (unsigned*)(part3 + 2 * (size_t)nb3);

    softmax_rows<<<(n_V + 255) / 256, 256, 0, stream>>>(
        trainable, fixedp, fixed_idx, P, ticket, n_fixed, n_V);

    gather_reduce<<<nb2 + nb3, 256, 0, stream>>>(s2, S2, nb2, s3, S3, nb3, P,
                                                 part2, part3, ticket,
                                                 (float*)d_out,
                                                 (float)S2, (float)S3);
}

// Round 3
// 117.190 us; speedup vs baseline: 1.5871x; 1.5871x over previous
//
#include <hip/hip_runtime.h>

// Model: generalized multinomial clique objective over 2- and 3-simplices.
// out = 2*obj2 + 4*obj3 where
//   obj2 = sum_edges (1 - 0.5 * p.q)
//   obj3 = sum_tris  (2 - p.q - p.r - q.r + (4/3) * sum_a p_a q_a r_a)
// with P = row-softmax of the scattered node-parameter matrix (n_L == 4).
//
// R1: removed same-cache-line atomics (were 34 cyc/atomic serialized).
// R2: occupancy was grid-limited; 4 items/thread + fused edge+tri kernel.
//     BASELINE 112.4 us.
// R3 FAILED: nontemporal index/input streams: 112.4 -> 118.4. P stays
//     L2-resident without help; nt reverted.
// R4 FAILED: last-block-done combine with per-block __threadfence():
//     112.4 -> 186.0. Device-scope release fence per block = L2
//     writeback/drain on non-coherent XCD L2s, serializing the kernel.
//     Reverted to 3-dispatch structure.
//     R4 profile showed gather is neither VALU- (2%) nor HBM-bound (2%):
//     it sits on the L1 miss path (7M random 16B gathers, ~100% L1 miss,
//     each pulling a dead 64B line fill).
// R5 (this round): issue P gathers with `sc0` (L1-bypass, served from L2)
//     via inline asm, killing the dead L1 line fills. Index streams and all
//     arithmetic order unchanged (bit-identical reduction).

#define NL 4

typedef float v4f __attribute__((ext_vector_type(4)));

__device__ __forceinline__ float dot4(v4f a, v4f b) {
    return a.x * b.x + a.y * b.y + a.z * b.z + a.w * b.w;
}

// L1-bypassing 16B gather: served from L2 (P is L2-resident), no L1 fill.
__device__ __forceinline__ v4f gather_sc0(const v4f* addr) {
    v4f r;
    asm volatile("global_load_dwordx4 %0, %1, off sc0"
                 : "=v"(r) : "v"(addr));
    return r;
}

__device__ __forceinline__ void wait_gathers() {
    asm volatile("s_waitcnt vmcnt(0)" ::: "memory");
    __builtin_amdgcn_sched_barrier(0);
}

__global__ void softmax_rows(const float* __restrict__ trainable,
                             const float* __restrict__ fixedp,
                             const int* __restrict__ fixed_idx,
                             float* __restrict__ P,
                             int n_fixed, int n_total) {
    int i = blockIdx.x * blockDim.x + threadIdx.x;
    if (i >= n_total) return;
    float4 v;
    int dst;
    if (i < n_fixed) {
        v = ((const float4*)fixedp)[i];
        dst = fixed_idx[i];
    } else {
        v = ((const float4*)trainable)[i - n_fixed];
        dst = i;  // trainable_indices = arange(n_fixed, n_V)
    }
    float m = fmaxf(fmaxf(v.x, v.y), fmaxf(v.z, v.w));
    float ex = __expf(v.x - m), ey = __expf(v.y - m);
    float ez = __expf(v.z - m), ew = __expf(v.w - m);
    float inv = 1.0f / (ex + ey + ez + ew);
    // P is immediately re-read ~70x per XCD by gather_reduce: keep cached.
    ((float4*)P)[dst] = make_float4(ex * inv, ey * inv, ez * inv, ew * inv);
}

// Fused gather-reduce. Blocks [0, nb2): 4 edges/thread. Blocks [nb2, nb2+nb3):
// 4 triples/thread. Block-level partials to distinct slots (no atomics).
__global__ void gather_reduce(const int* __restrict__ s2, int S2, int nb2,
                              const int* __restrict__ s3, int S3,
                              const float* __restrict__ P,
                              float* __restrict__ part2,
                              float* __restrict__ part3) {
    const v4f* __restrict__ Pv = (const v4f*)P;
    __shared__ float lds[8];
    int wid = threadIdx.x >> 6;

    if ((int)blockIdx.x < nb2) {
        int tid = blockIdx.x * blockDim.x + threadIdx.x;
        int base = tid * 4;
        float sum = 0.f;
        if (base + 4 <= S2) {
            const int4* s = (const int4*)s2;
            int4 a = s[tid * 2], b = s[tid * 2 + 1];
            v4f p0 = gather_sc0(Pv + a.x), q0 = gather_sc0(Pv + a.y);
            v4f p1 = gather_sc0(Pv + a.z), q1 = gather_sc0(Pv + a.w);
            v4f p2 = gather_sc0(Pv + b.x), q2 = gather_sc0(Pv + b.y);
            v4f p3 = gather_sc0(Pv + b.z), q3 = gather_sc0(Pv + b.w);
            wait_gathers();
            sum = dot4(p0, q0) + dot4(p1, q1) + dot4(p2, q2) + dot4(p3, q3);
        } else {
            for (int e = base; e < S2; ++e)
                sum += dot4(Pv[s2[2 * e]], Pv[s2[2 * e + 1]]);
        }
        #pragma unroll
        for (int off = 32; off > 0; off >>= 1) sum += __shfl_down(sum, off, 64);
        if ((threadIdx.x & 63) == 0) lds[wid] = sum;
        __syncthreads();
        if (threadIdx.x == 0)
            part2[blockIdx.x] = lds[0] + lds[1] + lds[2] + lds[3];
    } else {
        int bb = blockIdx.x - nb2;
        int tid = bb * blockDim.x + threadIdx.x;
        int base = tid * 4;
        float s_uvw = 0.f, s_t = 0.f;
        if (base + 4 <= S3) {
            const int4* s = (const int4*)s3;
            int4 a = s[tid * 3], b = s[tid * 3 + 1], c = s[tid * 3 + 2];
            int i0[4] = {a.x, a.w, b.z, c.y};
            int i1[4] = {a.y, b.x, b.w, c.z};
            int i2[4] = {a.z, b.y, c.x, c.w};
            v4f pp[4], qq[4], rr[4];
            #pragma unroll
            for (int k = 0; k < 4; ++k) {
                pp[k] = gather_sc0(Pv + i0[k]);
                qq[k] = gather_sc0(Pv + i1[k]);
                rr[k] = gather_sc0(Pv + i2[k]);
            }
            wait_gathers();
            #pragma unroll
            for (int k = 0; k < 4; ++k) {
                v4f p = pp[k], q = qq[k], r = rr[k];
                s_uvw += dot4(p, q) + dot4(p, r) + dot4(q, r);
                s_t += p.x * q.x * r.x + p.y * q.y * r.y
                     + p.z * q.z * r.z + p.w * q.w * r.w;
            }
        } else {
            for (int e = base; e < S3; ++e) {
                v4f p = Pv[s3[3 * e]], q = Pv[s3[3 * e + 1]], r = Pv[s3[3 * e + 2]];
                s_uvw += dot4(p, q) + dot4(p, r) + dot4(q, r);
                s_t += p.x * q.x * r.x + p.y * q.y * r.y
                     + p.z * q.z * r.z + p.w * q.w * r.w;
            }
        }
        #pragma unroll
        for (int off = 32; off > 0; off >>= 1) {
            s_uvw += __shfl_down(s_uvw, off, 64);
            s_t   += __shfl_down(s_t,   off, 64);
        }
        if ((threadIdx.x & 63) == 0) { lds[wid] = s_uvw; lds[4 + wid] = s_t; }
        __syncthreads();
        if (threadIdx.x == 0) {
            part3[2 * bb]     = lds[0] + lds[1] + lds[2] + lds[3];
            part3[2 * bb + 1] = lds[4] + lds[5] + lds[6] + lds[7];
        }
    }
}

__global__ void final_combine(const float* __restrict__ part2, int nb2,
                              const float* __restrict__ part3, int nb3,
                              float* __restrict__ out, float S2f, float S3f) {
    float dot2 = 0.f, uvw = 0.f, t = 0.f;
    for (int i = threadIdx.x; i < nb2; i += 256) dot2 += part2[i];
    for (int i = threadIdx.x; i < nb3; i += 256) {
        uvw += part3[2 * i];
        t   += part3[2 * i + 1];
    }
    #pragma unroll
    for (int off = 32; off > 0; off >>= 1) {
        dot2 += __shfl_down(dot2, off, 64);
        uvw  += __shfl_down(uvw,  off, 64);
        t    += __shfl_down(t,    off, 64);
    }
    __shared__ float lds[12];
    int wid = threadIdx.x >> 6;
    if ((threadIdx.x & 63) == 0) {
        lds[wid] = dot2; lds[4 + wid] = uvw; lds[8 + wid] = t;
    }
    __syncthreads();
    if (threadIdx.x == 0) {
        float D = lds[0] + lds[1] + lds[2] + lds[3];
        float U = lds[4] + lds[5] + lds[6] + lds[7];
        float T = lds[8] + lds[9] + lds[10] + lds[11];
        float obj2 = S2f - 0.5f * D;
        float obj3 = 2.f * S3f - U + (4.f / 3.f) * T;
        out[0] = 2.f * obj2 + 4.f * obj3;
    }
}

extern "C" void kernel_launch(void* const* d_in, const int* in_sizes, int n_in,
                              void* d_out, int out_size, void* d_ws, size_t ws_size,
                              hipStream_t stream) {
    const float* trainable = (const float*)d_in[0];
    const float* fixedp    = (const float*)d_in[1];
    const int*   fixed_idx = (const int*)d_in[2];
    const int*   s2        = (const int*)d_in[3];
    const int*   s3        = (const int*)d_in[4];

    int n_fixed = in_sizes[2];
    int n_L     = in_sizes[1] / n_fixed;   // == 4
    int n_train = in_sizes[0] / n_L;
    int n_V     = n_fixed + n_train;
    int S2      = in_sizes[3] / 2;
    int S3      = in_sizes[4] / 3;
    (void)n_L; (void)ws_size; (void)n_in; (void)out_size;

    float* P     = (float*)d_ws;                  // n_V * 4 floats
    float* part2 = P + (size_t)n_V * NL;
    int threads2 = (S2 + 3) / 4;
    int nb2      = (threads2 + 255) / 256;
    float* part3 = part2 + nb2;
    int threads3 = (S3 + 3) / 4;
    int nb3      = (threads3 + 255) / 256;

    softmax_rows<<<(n_V + 255) / 256, 256, 0, stream>>>(
        trainable, fixedp, fixed_idx, P, n_fixed, n_V);

    gather_reduce<<<nb2 + nb3, 256, 0, stream>>>(s2, S2, nb2, s3, S3, P,
                                                 part2, part3);

    final_combine<<<1, 256, 0, stream>>>(part2, nb2, part3, nb3,
                                         (float*)d_out, (float)S2, (float)S3);
}

// Round 4
// 112.641 us; speedup vs baseline: 1.6512x; 1.0404x over previous
//
#include <hip/hip_runtime.h>

// Model: generalized multinomial clique objective over 2- and 3-simplices.
// out = 2*obj2 + 4*obj3 where
//   obj2 = sum_edges (1 - 0.5 * p.q)
//   obj3 = sum_tris  (2 - p.q - p.r - q.r + (4/3) * sum_a p_a q_a r_a)
// with P = row-softmax of the scattered node-parameter matrix (n_L == 4).
//
// R1: removed same-cache-line atomics (were 34 cyc/atomic serialized).
// R2: 4 items/thread + fused edge+tri kernel. BASELINE 112.4 us.
// R3 FAILED: nontemporal streams 112.4 -> 118.4. nt reverted.
// R4 FAILED: per-block __threadfence() fused combine 112.4 -> 186.0
//     (device-scope release = L2 drain per block on non-coherent XCD L2s).
//     Profile: gather is ~2% VALU, ~2% HBM, 0 bank conflicts.
// R5 FAILED: sc0 L1-bypass gathers 112.4 -> 117.2. L1-fill theory dead.
// R6 (this round): the gather grid (2931 blocks) vs resident capacity
//     (2048) ran as 1 full + 1 43%-full batch = 71.5% utilization.
//     Persistent grid of exactly 2048 blocks; fine-grained chunks
//     (2 edges / 2 tris per thread) round-robined per block = 95.4%
//     packing. Register accumulation across chunks, one reduce/block.

#define NL 4
#define GRB 2048   // persistent blocks: 8 blocks/CU x 256 CU (4 waves each)

typedef float v4f __attribute__((ext_vector_type(4)));

__device__ __forceinline__ float dot4(v4f a, v4f b) {
    return a.x * b.x + a.y * b.y + a.z * b.z + a.w * b.w;
}

__global__ void softmax_rows(const float* __restrict__ trainable,
                             const float* __restrict__ fixedp,
                             const int* __restrict__ fixed_idx,
                             float* __restrict__ P,
                             int n_fixed, int n_total) {
    int i = blockIdx.x * blockDim.x + threadIdx.x;
    if (i >= n_total) return;
    float4 v;
    int dst;
    if (i < n_fixed) {
        v = ((const float4*)fixedp)[i];
        dst = fixed_idx[i];
    } else {
        v = ((const float4*)trainable)[i - n_fixed];
        dst = i;  // trainable_indices = arange(n_fixed, n_V)
    }
    float m = fmaxf(fmaxf(v.x, v.y), fmaxf(v.z, v.w));
    float ex = __expf(v.x - m), ey = __expf(v.y - m);
    float ez = __expf(v.z - m), ew = __expf(v.w - m);
    float inv = 1.0f / (ex + ey + ez + ew);
    ((float4*)P)[dst] = make_float4(ex * inv, ey * inv, ez * inv, ew * inv);
}

// Persistent-grid gather-reduce. Work is split into fine chunks:
//   chunk c in [0, nb2):        256 threads x 2 edges  (one int4 index load)
//   chunk c in [nb2, nbTot):    256 threads x 2 tris   (three int2 loads)
// Block b processes chunks b, b+GRB, b+2*GRB, ... accumulating all three
// partial sums in registers; one reduction + 3 partial slots per block.
__global__ void gather_reduce(const int* __restrict__ s2, int S2, int nb2,
                              const int* __restrict__ s3, int S3, int nbTot,
                              const float* __restrict__ P,
                              float* __restrict__ part2,
                              float* __restrict__ part3) {
    const v4f* __restrict__ Pv = (const v4f*)P;
    __shared__ float lds[12];
    int wid = threadIdx.x >> 6;

    const int U2 = S2 >> 1;   // 2-edge units
    const int V3 = S3 >> 1;   // 2-tri units

    float sum2 = 0.f, s_uvw = 0.f, s_t = 0.f;

    for (int vb = blockIdx.x; vb < nbTot; vb += gridDim.x) {
        if (vb < nb2) {
            int u = vb * 256 + (int)threadIdx.x;
            if (u < U2) {
                int4 a = ((const int4*)s2)[u];          // edges 2u, 2u+1
                v4f p0 = Pv[a.x], q0 = Pv[a.y];
                v4f p1 = Pv[a.z], q1 = Pv[a.w];
                sum2 += dot4(p0, q0) + dot4(p1, q1);
            }
        } else {
            int v = (vb - nb2) * 256 + (int)threadIdx.x;
            if (v < V3) {
                const int2* s = (const int2*)s3;        // tris 2v, 2v+1
                int2 a = s[3 * v], b = s[3 * v + 1], c = s[3 * v + 2];
                v4f p = Pv[a.x], q = Pv[a.y], r = Pv[b.x];
                s_uvw += dot4(p, q) + dot4(p, r) + dot4(q, r);
                s_t += p.x * q.x * r.x + p.y * q.y * r.y
                     + p.z * q.z * r.z + p.w * q.w * r.w;
                p = Pv[b.y]; q = Pv[c.x]; r = Pv[c.y];
                s_uvw += dot4(p, q) + dot4(p, r) + dot4(q, r);
                s_t += p.x * q.x * r.x + p.y * q.y * r.y
                     + p.z * q.z * r.z + p.w * q.w * r.w;
            }
        }
    }

    // odd-count safety tails (S2/S3 are even in this problem)
    if (blockIdx.x == 0 && threadIdx.x == 0) {
        if (S2 & 1) {
            int e = S2 - 1;
            sum2 += dot4(Pv[s2[2 * e]], Pv[s2[2 * e + 1]]);
        }
        if (S3 & 1) {
            int e = S3 - 1;
            v4f p = Pv[s3[3 * e]], q = Pv[s3[3 * e + 1]], r = Pv[s3[3 * e + 2]];
            s_uvw += dot4(p, q) + dot4(p, r) + dot4(q, r);
            s_t += p.x * q.x * r.x + p.y * q.y * r.y
                 + p.z * q.z * r.z + p.w * q.w * r.w;
        }
    }

    #pragma unroll
    for (int off = 32; off > 0; off >>= 1) {
        sum2  += __shfl_down(sum2,  off, 64);
        s_uvw += __shfl_down(s_uvw, off, 64);
        s_t   += __shfl_down(s_t,   off, 64);
    }
    if ((threadIdx.x & 63) == 0) {
        lds[wid] = sum2; lds[4 + wid] = s_uvw; lds[8 + wid] = s_t;
    }
    __syncthreads();
    if (threadIdx.x == 0) {
        part2[blockIdx.x]         = lds[0] + lds[1] + lds[2] + lds[3];
        part3[2 * blockIdx.x]     = lds[4] + lds[5] + lds[6] + lds[7];
        part3[2 * blockIdx.x + 1] = lds[8] + lds[9] + lds[10] + lds[11];
    }
}

__global__ void final_combine(const float* __restrict__ part2, int nb2,
                              const float* __restrict__ part3, int nb3,
                              float* __restrict__ out, float S2f, float S3f) {
    float dot2 = 0.f, uvw = 0.f, t = 0.f;
    for (int i = threadIdx.x; i < nb2; i += 256) dot2 += part2[i];
    for (int i = threadIdx.x; i < nb3; i += 256) {
        uvw += part3[2 * i];
        t   += part3[2 * i + 1];
    }
    #pragma unroll
    for (int off = 32; off > 0; off >>= 1) {
        dot2 += __shfl_down(dot2, off, 64);
        uvw  += __shfl_down(uvw,  off, 64);
        t    += __shfl_down(t,    off, 64);
    }
    __shared__ float lds[12];
    int wid = threadIdx.x >> 6;
    if ((threadIdx.x & 63) == 0) {
        lds[wid] = dot2; lds[4 + wid] = uvw; lds[8 + wid] = t;
    }
    __syncthreads();
    if (threadIdx.x == 0) {
        float D = lds[0] + lds[1] + lds[2] + lds[3];
        float U = lds[4] + lds[5] + lds[6] + lds[7];
        float T = lds[8] + lds[9] + lds[10] + lds[11];
        float obj2 = S2f - 0.5f * D;
        float obj3 = 2.f * S3f - U + (4.f / 3.f) * T;
        out[0] = 2.f * obj2 + 4.f * obj3;
    }
}

extern "C" void kernel_launch(void* const* d_in, const int* in_sizes, int n_in,
                              void* d_out, int out_size, void* d_ws, size_t ws_size,
                              hipStream_t stream) {
    const float* trainable = (const float*)d_in[0];
    const float* fixedp    = (const float*)d_in[1];
    const int*   fixed_idx = (const int*)d_in[2];
    const int*   s2        = (const int*)d_in[3];
    const int*   s3        = (const int*)d_in[4];

    int n_fixed = in_sizes[2];
    int n_L     = in_sizes[1] / n_fixed;   // == 4
    int n_train = in_sizes[0] / n_L;
    int n_V     = n_fixed + n_train;
    int S2      = in_sizes[3] / 2;
    int S3      = in_sizes[4] / 3;
    (void)n_L; (void)ws_size; (void)n_in; (void)out_size;

    float* P     = (float*)d_ws;                  // n_V * 4 floats
    float* part2 = P + (size_t)n_V * NL;          // GRB floats
    float* part3 = part2 + GRB;                   // 2*GRB floats

    int U2    = S2 >> 1;
    int V3    = S3 >> 1;
    int nb2   = (U2 + 255) / 256;                 // edge chunks
    int nb3   = (V3 + 255) / 256;                 // tri chunks
    int nbTot = nb2 + nb3;

    softmax_rows<<<(n_V + 255) / 256, 256, 0, stream>>>(
        trainable, fixedp, fixed_idx, P, n_fixed, n_V);

    gather_reduce<<<GRB, 256, 0, stream>>>(s2, S2, nb2, s3, S3, nbTot, P,
                                           part2, part3);

    final_combine<<<1, 256, 0, stream>>>(part2, GRB, part3, GRB,
                                         (float*)d_out, (float)S2, (float)S3);
}